// Round 1
// 3988.909 us; speedup vs baseline: 1.7841x; 1.7841x over previous
//
#include <hip/hip_runtime.h>
#include <stdint.h>

// Round 3: kill the per-step serialization hot spots in rnn_scan.
//  (a) Barrier: 64 same-address atomic fetch_adds/chain/step (serialized RMW at the
//      memory-side LLC) -> monotonic per-WG flag array, 64B-strided, plain sc0/sc1
//      stores + one-wave parallel poll with __all().  No RMW anywhere.
//  (b) Producer tail: out[] HBM stores were drained by the pre-signal vmcnt(0).
//      They are now deferred to the top of the NEXT step, overlapping the h-load.
//  (c) h broadcast staging: 16x8B atomic loads -> 8x16B global_load_dwordx4 sc0 sc1
//      (L1+L2 bypass, LLC-coherent), one vmcnt(0) + sched_barrier(0) before LDS writes.

#define TT 1024
#define BB 32
#define DD 1024
#define GM (TT * BB)   // 32768
#define GN 3072
#define GK 1024

typedef __attribute__((ext_vector_type(8))) __bf16 bf16x8;
typedef __attribute__((ext_vector_type(8))) unsigned short us8;
typedef __attribute__((ext_vector_type(4))) float f32x4;
typedef __attribute__((ext_vector_type(4))) unsigned int u32x4;
typedef unsigned short ushort_t;
typedef unsigned long long ull_t;

__device__ __forceinline__ unsigned short f2bf(float f) {
    unsigned u = __builtin_bit_cast(unsigned, f);
    return (unsigned short)((u + 0x8000u) >> 16);  // round-half-up; inputs are finite
}
__device__ __forceinline__ float bf2f(unsigned short h) {
    unsigned u = ((unsigned)h) << 16;
    return __builtin_bit_cast(float, u);
}

// ---------------------------------------------------------------- cvt fp32->bf16
__global__ __launch_bounds__(256) void cvt_f32_bf16(const float4* __restrict__ src,
                                                    ushort4* __restrict__ dst, int n4) {
    int i = blockIdx.x * 256 + threadIdx.x;
    int stride = gridDim.x * 256;
    for (; i < n4; i += stride) {
        float4 v = src[i];
        ushort4 o;
        o.x = f2bf(v.x); o.y = f2bf(v.y); o.z = f2bf(v.z); o.w = f2bf(v.w);
        dst[i] = o;
    }
}

// ---------------------------------------------------------------- GEMM: P = Xbf @ Wcat^T
// 128x128 tile, BK=64, 4 waves in 2x2, XOR-swizzled LDS (16B chunk ^ (row&7)) -> 2-way (free).
#define SUPER 16
__global__ __launch_bounds__(256) void gemm_xproj(const ushort_t* __restrict__ A,   // 32768x1024 bf16
                                                  const ushort_t* __restrict__ Bw,  // 3072x1024 bf16
                                                  ushort_t* __restrict__ P) {       // 32768x3072 bf16
    __shared__ ushort_t As[128 * 64];
    __shared__ ushort_t Bs[128 * 64];

    int bid = blockIdx.x;
    int st = bid / (SUPER * 24);
    int r  = bid % (SUPER * 24);
    int tm = st * SUPER + (r & (SUPER - 1));   // supertile order: 16 M-tiles share A in L2/LLC
    int tn = r / SUPER;

    int tid = threadIdx.x;
    int lane = tid & 63, wv = tid >> 6;
    int wm = wv >> 1, wn = wv & 1;
    int l15 = lane & 15, q = lane >> 4;

    f32x4 acc[4][4];
#pragma unroll
    for (int mi = 0; mi < 4; mi++)
#pragma unroll
        for (int ni = 0; ni < 4; ni++) acc[mi][ni] = (f32x4){0.f, 0.f, 0.f, 0.f};

    const ushort_t* Abase = A + (size_t)(tm * 128) * GK;
    const ushort_t* Bbase = Bw + (size_t)(tn * 128) * GK;
    int c8 = tid & 7, rr = tid >> 3;  // rr: 0..31

    for (int kit = 0; kit < 16; kit++) {
        int k0 = kit * 64;
        if (kit) __syncthreads();
#pragma unroll
        for (int p = 0; p < 4; p++) {
            int row = p * 32 + rr;
            int sw = c8 ^ (row & 7);
            uint4 va = *(const uint4*)(Abase + (size_t)row * GK + k0 + c8 * 8);
            *(uint4*)&As[row * 64 + sw * 8] = va;
            uint4 vb = *(const uint4*)(Bbase + (size_t)row * GK + k0 + c8 * 8);
            *(uint4*)&Bs[row * 64 + sw * 8] = vb;
        }
        __syncthreads();
#pragma unroll
        for (int ks = 0; ks < 2; ks++) {
            bf16x8 af[4], bfr[4];
#pragma unroll
            for (int mi = 0; mi < 4; mi++) {
                int rl = wm * 64 + mi * 16 + l15;
                int sw = (ks * 4 + q) ^ (rl & 7);
                af[mi] = *(const bf16x8*)&As[rl * 64 + sw * 8];
            }
#pragma unroll
            for (int ni = 0; ni < 4; ni++) {
                int rl = wn * 64 + ni * 16 + l15;
                int sw = (ks * 4 + q) ^ (rl & 7);
                bfr[ni] = *(const bf16x8*)&Bs[rl * 64 + sw * 8];
            }
#pragma unroll
            for (int mi = 0; mi < 4; mi++)
#pragma unroll
                for (int ni = 0; ni < 4; ni++)
                    acc[mi][ni] = __builtin_amdgcn_mfma_f32_16x16x32_bf16(af[mi], bfr[ni], acc[mi][ni], 0, 0, 0);
        }
    }
    // epilogue: C/D layout col=lane&15, row=(lane>>4)*4+reg  [verified m89/m91]
#pragma unroll
    for (int mi = 0; mi < 4; mi++)
#pragma unroll
        for (int ni = 0; ni < 4; ni++) {
            int n = tn * 128 + wn * 64 + ni * 16 + l15;
#pragma unroll
            for (int i = 0; i < 4; i++) {
                int m = tm * 128 + wm * 64 + mi * 16 + q * 4 + i;
                P[(size_t)m * GN + n] = f2bf(acc[mi][ni][i]);
            }
        }
}

// ---------------------------------------------------------------- persistent RNN scan
// 128 WGs: bg = blockIdx>>6 (2 chains of 16 batches), slice = blockIdx&63 (16 dims each).
// Weights as B-frags in registers: wf[mat][ks], wave wv covers k in [wv*256, wv*256+256).
// Cross-WG handoff: sc0/sc1 (L1+L2-bypass, LLC-coherent) plain loads/stores; barrier is a
// monotonic per-WG flag (flags[g] = completed steps), no atomic RMW.
__global__ __launch_bounds__(256) void rnn_scan(
    const float* __restrict__ Ua, const float* __restrict__ Ub, const float* __restrict__ Wh,
    const float* __restrict__ ba, const float* __restrict__ bb, const float* __restrict__ bv,
    const ushort_t* __restrict__ P,     // 32768x3072 bf16
    ushort_t* __restrict__ hbuf,        // 2 x 32 x 1024 bf16 (double-buffered broadcast)
    unsigned int* __restrict__ flags,   // 128 x 16 uints: flag for WG g at flags[g*16] (64B stride)
    float* __restrict__ out) {

    __shared__ __align__(16) ushort_t Hs[16 * DD];    // 32KB staged h (swizzled)
    __shared__ float Red[4][3][16][16];               // 12KB K-split partials
    __shared__ __align__(16) ushort_t Hloc[16][16];   // 512B h repack for 8B stores

    int g = blockIdx.x;
    int slice = g & 63, bg = g >> 6;
    int e0 = slice * 16;
    int tid = threadIdx.x, lane = tid & 63, wv = tid >> 6;
    int l15 = lane & 15, q = lane >> 4;

    // ---- preload recurrent weight fragments into registers (96 VGPR/lane)
    bf16x8 wf[3][8];
#pragma unroll
    for (int nt = 0; nt < 3; nt++) {
        const float* Um = (nt == 0) ? Ua : (nt == 1) ? Ub : Wh;
#pragma unroll
        for (int ks = 0; ks < 8; ks++) {
            int e = e0 + l15;
            int d = wv * 256 + ks * 32 + q * 8;
            const float* p = Um + (size_t)e * DD + d;
            us8 u;
#pragma unroll
            for (int j = 0; j < 8; j++) u[j] = f2bf(p[j]);
            wf[nt][ks] = __builtin_bit_cast(bf16x8, u);
        }
    }

    // ---- per-thread ownership for the elementwise epilogue: thread = (batch, dim)
    int bcomb = tid >> 4;            // 0..15 batch-local
    int ncomb = tid & 15;            // 0..15 dim-local
    int bglob = bg * 16 + bcomb;
    int ecomb = e0 + ncomb;
    float bias_a = ba[ecomb], bias_b = bb[ecomb], bias_v = bv[ecomb];
    float hreg = 0.f;                // fp32 master h state lives here across all steps
    int hoff = bglob * DD + ecomb;

    // h store lane mapping (wave 0 only): batch b = tid>>2, dim-quad c4 = tid&3
    int sb = tid >> 2, sc4 = tid & 3;

    unsigned int* myflag = flags + (size_t)g * 16;
    const unsigned int* pollflag = flags + (size_t)(bg * 64 + lane) * 16;

    // staging geometry: 16B chunk cc is t-invariant; row m = 2*j + thi
    int cc = tid & 127, thi = tid >> 7;

    float hn_keep = 0.f, o1_keep = 0.f;

    for (int t = 0; t < TT; t++) {
        // deferred out stores from step t-1: overlap the h-load / flag latency below
        if (t) {
            out[(size_t)(TT + t) * (BB * DD) + hoff] = hn_keep;       // h[t]
            out[(size_t)(t - 1) * (BB * DD) + hoff] = o1_keep;        // out[t-1]
        }

        // x-projection values for this step (independent of h -> issue early, drain at vmcnt(0))
        const ushort_t* pp = P + ((size_t)t * BB + bglob) * GN + ecomb;
        unsigned short pax = pp[0];
        unsigned short pbx = pp[DD];
        unsigned short pwx = pp[2 * DD];

        // stage h (16 batches x 1024 d, bf16): 8 x 16B LLC-coherent loads per thread
        const ushort_t* hsrc = hbuf + (t & 1) * (BB * DD) + bg * 16 * DD;
        u32x4 hv[8];
#pragma unroll
        for (int j = 0; j < 8; j++) {
            const ushort_t* ap = hsrc + (size_t)(2 * j + thi) * DD + cc * 8;
            asm volatile("global_load_dwordx4 %0, %1, off sc0 sc1"
                         : "=v"(hv[j]) : "v"(ap) : "memory");
        }
        asm volatile("s_waitcnt vmcnt(0)" ::: "memory");
        __builtin_amdgcn_sched_barrier(0);
#pragma unroll
        for (int j = 0; j < 8; j++) {
            int m = 2 * j + thi;
            int ccsw = (cc & ~7) | ((cc & 7) ^ (m & 7));
            *(u32x4*)&Hs[m * DD + ccsw * 8] = hv[j];
        }
        __syncthreads();

        // MFMA: each wave does its K-quarter for all 3 matrices
        f32x4 a0 = {0.f,0.f,0.f,0.f}, a1 = {0.f,0.f,0.f,0.f}, a2 = {0.f,0.f,0.f,0.f};
#pragma unroll
        for (int ks = 0; ks < 8; ks++) {
            int c = wv * 32 + ks * 4 + q;
            int csw = (c & ~7) | ((c & 7) ^ (l15 & 7));
            bf16x8 af = *(const bf16x8*)&Hs[l15 * DD + csw * 8];
            a0 = __builtin_amdgcn_mfma_f32_16x16x32_bf16(af, wf[0][ks], a0, 0, 0, 0);
            a1 = __builtin_amdgcn_mfma_f32_16x16x32_bf16(af, wf[1][ks], a1, 0, 0, 0);
            a2 = __builtin_amdgcn_mfma_f32_16x16x32_bf16(af, wf[2][ks], a2, 0, 0, 0);
        }
#pragma unroll
        for (int i = 0; i < 4; i++) {
            Red[wv][0][q * 4 + i][l15] = a0[i];
            Red[wv][1][q * 4 + i][l15] = a1[i];
            Red[wv][2][q * 4 + i][l15] = a2[i];
        }
        __syncthreads();

        // combine: K-reduce across waves, gates, h update
        float pa = 0.f, pb = 0.f, pv = 0.f;
#pragma unroll
        for (int w = 0; w < 4; w++) {
            pa += Red[w][0][bcomb][ncomb];
            pb += Red[w][1][bcomb][ncomb];
            pv += Red[w][2][bcomb][ncomb];
        }
        float aval = pa + bf2f(pax) + bias_a;
        float bval = pb + bf2f(pbx) + bias_b;
        float vval = pv + bf2f(pwx) + bias_v;
        float alpha = 1.f / (1.f + __expf(-aval));
        float beta  = 1.f / (1.f + __expf(-bval));
        float vtan  = tanhf(vval);
        float hn = alpha * hreg + beta * vtan;
        hreg = hn;
        float sg = 1.f / (1.f + __expf(-hn));
        hn_keep = hn;
        o1_keep = hn * hn * sg;          // h*silu(h), stored next step (overlapped)
        Hloc[bcomb][ncomb] = f2bf(hn);   // repack for 8B stores

        if (t < TT - 1) {
            __syncthreads();                          // Hloc ready
            if (tid < 64) {                           // wave 0: 8B LLC-coherent h stores
                ull_t v = *(const ull_t*)&Hloc[sb][sc4 * 4];
                ushort_t* dst = hbuf + ((t + 1) & 1) * (BB * DD)
                              + (bg * 16 + sb) * DD + e0 + sc4 * 4;
                asm volatile("global_store_dwordx2 %0, %1, off sc0 sc1"
                             :: "v"(dst), "v"(v) : "memory");
            }
            // drain ONLY the h store (out stores were issued a full step earlier)
            asm volatile("s_waitcnt vmcnt(0)" ::: "memory");
            __syncthreads();
            if (tid == 0) {
                unsigned int tv = (unsigned)(t + 1);
                asm volatile("global_store_dword %0, %1, off sc0 sc1"
                             :: "v"(myflag), "v"(tv) : "memory");
            }
            // wave 0 polls all 64 producer flags of this chain in parallel
            if (tid < 64) {
                for (;;) {
                    unsigned int fv;
                    asm volatile("global_load_dword %0, %1, off sc0 sc1\n\t"
                                 "s_waitcnt vmcnt(0)"
                                 : "=v"(fv) : "v"(pollflag) : "memory");
                    if (__all((int)(fv >= (unsigned)(t + 1)))) break;
                    __builtin_amdgcn_s_sleep(1);
                }
            }
            __syncthreads();
        }
    }
    // final step's outputs
    out[(size_t)(2 * TT) * (BB * DD) + hoff] = hn_keep;               // h[TT]
    out[(size_t)(TT - 1) * (BB * DD) + hoff] = o1_keep;               // out[TT-1]
}

// ---------------------------------------------------------------- launch
extern "C" void kernel_launch(void* const* d_in, const int* in_sizes, int n_in,
                              void* d_out, int out_size, void* d_ws, size_t ws_size,
                              hipStream_t stream) {
    const float* x   = (const float*)d_in[0];
    const float* Wa  = (const float*)d_in[1];
    const float* Uaw = (const float*)d_in[2];
    const float* bal = (const float*)d_in[3];
    const float* Wb  = (const float*)d_in[4];
    const float* Ubw = (const float*)d_in[5];
    const float* bbe = (const float*)d_in[6];
    const float* Whw = (const float*)d_in[7];
    const float* Wx  = (const float*)d_in[8];
    const float* bw  = (const float*)d_in[9];
    float* out = (float*)d_out;

    // ws layout (262.1 MiB total):
    char* ws = (char*)d_ws;
    ushort_t* P    = (ushort_t*)ws;                                   // 201326592 B
    ushort_t* xbf  = (ushort_t*)(ws + 201326592);                     //  67108864 B
    ushort_t* Wcat = (ushort_t*)(ws + 201326592 + 67108864);          //   6291456 B
    ushort_t* hbuf = (ushort_t*)(ws + 274726912);                     //    131072 B
    unsigned int* flags = (unsigned int*)(ws + 274726912 + 131072);   //      8192 B (128 x 64B)

    hipMemsetAsync(hbuf, 0, 131072 + 8192, stream);                       // h0 + flags
    hipMemsetAsync(out + (size_t)TT * (BB * DD), 0, (BB * DD) * sizeof(float), stream);  // h[0] output

    cvt_f32_bf16<<<512, 256, 0, stream>>>((const float4*)x,  (ushort4*)xbf,  (GM * GK) / 4);
    cvt_f32_bf16<<<64, 256, 0, stream>>>((const float4*)Wa, (ushort4*)Wcat, (DD * DD) / 4);
    cvt_f32_bf16<<<64, 256, 0, stream>>>((const float4*)Wb, (ushort4*)(Wcat + DD * DD), (DD * DD) / 4);
    cvt_f32_bf16<<<64, 256, 0, stream>>>((const float4*)Wx, (ushort4*)(Wcat + 2 * DD * DD), (DD * DD) / 4);

    gemm_xproj<<<(GM / 128) * (GN / 128), 256, 0, stream>>>(xbf, Wcat, P);

    rnn_scan<<<128, 256, 0, stream>>>(Uaw, Ubw, Whw, bal, bbe, bw, P, hbuf, flags, out);
}